// Round 1
// 254.145 us; speedup vs baseline: 1.0329x; 1.0329x over previous
//
#include <hip/hip_runtime.h>
#include <cmath>
#include <stdint.h>

#define B_    8
#define NIN_  256
#define D_    128
#define K_    1024
#define N_    4096
#define P_    (B_ * N_)          // 32768 positions
#define MARGIN_M 1e-4f           // screening margin in m = dsq/den^2 domain

typedef __attribute__((ext_vector_type(8))) short bf16x8;   // 8 bf16 (4 VGPRs)
typedef __attribute__((ext_vector_type(4))) float f32x4;    // 4 fp32 acc

// ---- workspace layout (bytes), ~51 MB ----
#define WS_ZSUM   0                 // K*D*4 = 524288 (zeroed)
#define WS_CNT    524288            // 4096           (zeroed)
#define WS_FLAGC  528384            // 4096           (zeroed)
#define WS_MEMSET 532480
#define WS_OFF    532480
#define WS_QSQ    536576
#define WS_QNORM  540672
#define WS_KSTAR  544768            // P*4
#define WS_RANK   675840
#define WS_PLIST  806912
#define WS_KLIST  937984
#define WS_FLIST  1069056
#define WS_WT     1200128           // NIN*D*4
#define WS_ZPM    1331200           // P*D*4 = 16 MiB (p-major fp32 ze)
#define WS_ZESQ   18108416          // P*4
#define WS_ZEN    18239488          // P*4
#define WS_ZE2F   18370560          // 2048 pt x 12 c x 64 lane x 16B = 24 MiB
#define WS_EMB2F  43536384          // 64 kt x 12 x 64 x 16B = 768 KiB
#define WS_VAL1   44322816          // 16*P*4 = 2 MiB
#define WS_IDX1   46419968          // 2 MiB
#define WS_VAL2   48517120          // 2 MiB

__device__ inline unsigned short f2bf(float v) {          // RTNE fp32->bf16
  union { float f; uint32_t u; } c; c.f = v;
  return (unsigned short)((c.u + 0x7FFFu + ((c.u >> 16) & 1u)) >> 16);
}
__device__ inline float bf2f(unsigned short b) {
  union { float f; uint32_t u; } c; c.u = ((uint32_t)b) << 16; return c.f;
}
__device__ inline uint32_t pack2(float a, float b, int lo) {
  unsigned short ha = f2bf(a); if (lo) ha = f2bf(a - bf2f(ha));
  unsigned short hb = f2bf(b); if (lo) hb = f2bf(b - bf2f(hb));
  return (uint32_t)ha | ((uint32_t)hb << 16);
}

// ---- prep: Wt transpose, q_sq/q_norm, emb2f B-fragments ----
__global__ __launch_bounds__(256) void prep_kernel(
    const float* __restrict__ W, const float* __restrict__ emb,
    float* __restrict__ Wt, float* __restrict__ q_sq, float* __restrict__ q_norm,
    uint4* __restrict__ emb2f)
{
  const int tid = threadIdx.x;
  const int bid = blockIdx.x;
  if (bid < 128) {
    int t = bid * 256 + tid;
    int c = t >> 7, d = t & 127;
    Wt[t] = W[d * NIN_ + c];
  } else if (bid < 132) {
    int k = (bid - 128) * 256 + tid;
    const float* e = emb + (size_t)k * D_;
    float s = 0.f;
    #pragma unroll 8
    for (int d = 0; d < D_; ++d) s = fmaf(e[d], e[d], s);
    q_sq[k] = s;
    q_norm[k] = sqrtf(s);
  } else {
    const int kt = bid - 132;             // 0..63
    #pragma unroll
    for (int i = 0; i < 3; ++i) {
      int f    = i * 256 + tid;           // 0..767
      int c    = f >> 6;
      int lane = f & 63;
      int k    = kt * 16 + (lane & 15);
      int q    = lane >> 4;
      int kk0  = c * 32 + q * 8;
      int lo   = (kk0 >> 7) == 1;
      int d0   = kk0 & 127;
      float4 v0 = *(const float4*)&emb[(size_t)k * D_ + d0];
      float4 v1 = *(const float4*)&emb[(size_t)k * D_ + d0 + 4];
      uint4 u;
      u.x = pack2(v0.x, v0.y, lo);
      u.y = pack2(v0.z, v0.w, lo);
      u.z = pack2(v1.x, v1.y, lo);
      u.w = pack2(v1.z, v1.w, lo);
      emb2f[(size_t)kt * 768 + f] = u;
    }
  }
}

// ---- ze = W @ z: p-major fp32, ze_sq/ze_norm, ze2f A-fragments ----
__global__ __launch_bounds__(512) void ze_kernel(
    const float* __restrict__ z, const float* __restrict__ Wt,
    float* __restrict__ ze_pm, float* __restrict__ ze_sq,
    float* __restrict__ ze_norm, uint4* __restrict__ ze2f)
{
  __shared__ float tile[64][132];     // +4 pad
  __shared__ float sqpart[8][64];
  const int t    = threadIdx.x;
  const int lane = t & 63;
  const int wv   = __builtin_amdgcn_readfirstlane(t >> 6);   // 0..7
  const int p    = blockIdx.x * 64 + lane;
  const int b    = p >> 12;
  const int n    = p & (N_ - 1);

  float acc[16];
  #pragma unroll
  for (int j = 0; j < 16; ++j) acc[j] = 0.f;
  const float* zp = z + (size_t)b * NIN_ * N_ + n;
  const float* wp = Wt + wv * 16;
  #pragma unroll 4
  for (int c = 0; c < NIN_; ++c) {
    float zv = zp[(size_t)c * N_];                 // coalesced v-load
    #pragma unroll
    for (int j = 0; j < 16; ++j)
      acc[j] = fmaf(wp[c * D_ + j], zv, acc[j]);   // wave-uniform -> s_load
  }
  #pragma unroll
  for (int j = 0; j < 16; ++j) tile[lane][wv * 16 + j] = acc[j];
  float s = 0.f;
  #pragma unroll
  for (int j = 0; j < 16; ++j) s = fmaf(acc[j], acc[j], s);
  sqpart[wv][lane] = s;
  __syncthreads();
  if (wv == 0) {                        // same sum order as round 4 (passed)
    float tt = sqpart[0][lane];
    #pragma unroll
    for (int w = 1; w < 8; ++w) tt += sqpart[w][lane];
    ze_sq[p] = tt;
    ze_norm[p] = sqrtf(tt);
  }
  // p-major fp32 store via LDS transpose
  const int row = t >> 5;               // 0..15
  const int c4  = (t & 31) * 4;         // 0..124
  #pragma unroll
  for (int r = 0; r < 4; ++r) {
    int pr = r * 16 + row;
    float4 v = *(const float4*)&tile[pr][c4];
    *(float4*)&ze_pm[(size_t)(blockIdx.x * 64 + pr) * D_ + c4] = v;
  }
  // ze2f A-fragments: 4 pos-tiles x 768 frags = 3072, 6/thread, vectorized
  #pragma unroll
  for (int i = 0; i < 6; ++i) {
    int f    = i * 512 + t;             // 0..3071
    int lane_f = f & 63;
    int g    = f >> 6;                  // 0..47 = lpt*12 + c
    int c    = g % 12;
    int lpt  = g / 12;
    int pl   = lpt * 16 + (lane_f & 15);
    int q    = lane_f >> 4;
    int kk0  = c * 32 + q * 8;
    int lo   = (kk0 >> 7) == 2;
    int d0   = kk0 & 127;
    float4 v0 = *(const float4*)&tile[pl][d0];
    float4 v1 = *(const float4*)&tile[pl][d0 + 4];
    uint4 u;
    u.x = pack2(v0.x, v0.y, lo);
    u.y = pack2(v0.z, v0.w, lo);
    u.z = pack2(v1.x, v1.y, lo);
    u.w = pack2(v1.z, v1.w, lo);
    ze2f[((size_t)(blockIdx.x * 4 + lpt) * 12 + c) * 64 + lane_f] = u;
  }
}

// ---- MFMA GEMM-argmin, barrier-free direct-load version.
// Each wave owns a 64-pos x 64-code job; fragments loaded straight from
// global (L2) in per-lane MFMA layout; register double-buffer over the
// 12 c-chunks; no LDS, no __syncthreads. XCD-sliced: blockIdx&7 picks the
// XCD (dispatch round-robin heuristic), each XCD owns a 64-posblock slice
// of ze2f (3 MB) + all of emb2f (768 KB) -> fits 4 MB per-XCD L2.
// Numerics identical to previous round (same MFMA order, same epilogue).
__global__ __launch_bounds__(256, 3) void mfma_argmin_kernel(
    const uint4* __restrict__ ze2f, const uint4* __restrict__ emb2f,
    const float* __restrict__ ze_sq, const float* __restrict__ ze_norm,
    const float* __restrict__ q_sq, const float* __restrict__ q_norm,
    float* __restrict__ val1, int* __restrict__ idx1, float* __restrict__ val2)
{
  const int tid  = threadIdx.x;
  const int lane = tid & 63;
  const int w    = __builtin_amdgcn_readfirstlane(tid >> 6);  // 0..3
  const int x    = blockIdx.x & 7;          // XCD slice
  const int ib   = blockIdx.x >> 3;         // 0..255 within XCD
  const int pb2  = x * 64 + (ib & 63);      // pos-block of 64   (0..511)
  const int kbb  = (ib >> 6) * 4 + w;       // code-block of 64  (0..15)

  // frag (pt,c) at ze2f[(pt*12+c)*64+lane]; pt = pb2*4+ii
  const uint4* a_base = ze2f  + (size_t)pb2 * 3072 + lane;
  // frag (ct,c) at emb2f[ct*768 + c*64 + lane]; ct = kbb*4+jj
  const uint4* b_base = emb2f + (size_t)kbb * 3072 + lane;

  f32x4 acc[4][4];
  #pragma unroll
  for (int ii = 0; ii < 4; ++ii)
    #pragma unroll
    for (int jj = 0; jj < 4; ++jj) acc[ii][jj] = (f32x4){0.f, 0.f, 0.f, 0.f};

  uint4 af[2][4], bf[2][4];
  #pragma unroll
  for (int ii = 0; ii < 4; ++ii) af[0][ii] = a_base[ii * 768];
  #pragma unroll
  for (int jj = 0; jj < 4; ++jj) bf[0][jj] = b_base[jj * 768];

  #pragma unroll
  for (int c = 0; c < 12; ++c) {
    const int cur = c & 1, nxt = cur ^ 1;
    if (c + 1 < 12) {                       // prefetch next chunk into regs
      #pragma unroll
      for (int ii = 0; ii < 4; ++ii)
        af[nxt][ii] = a_base[ii * 768 + (c + 1) * 64];
      #pragma unroll
      for (int jj = 0; jj < 4; ++jj)
        bf[nxt][jj] = b_base[jj * 768 + (c + 1) * 64];
    }
    #pragma unroll
    for (int ii = 0; ii < 4; ++ii) {
      union { uint4 u; bf16x8 h; } au; au.u = af[cur][ii];
      #pragma unroll
      for (int jj = 0; jj < 4; ++jj) {
        union { uint4 u; bf16x8 h; } bu; bu.u = bf[cur][jj];
        acc[ii][jj] = __builtin_amdgcn_mfma_f32_16x16x32_bf16(au.h, bu.h,
                                                              acc[ii][jj], 0, 0, 0);
      }
    }
  }

  // ---- epilogue: identical math/order to previous round ----
  const int col = lane & 15;
  const int q   = lane >> 4;
  float qsq_l[4], qn_l[4]; int kg[4];
  #pragma unroll
  for (int j = 0; j < 4; ++j) {
    kg[j]    = kbb * 64 + j * 16 + col;
    qsq_l[j] = q_sq[kg[j]];
    qn_l[j]  = q_norm[kg[j]];
  }
  const int g = kbb;
  #pragma unroll
  for (int ii = 0; ii < 4; ++ii) {
    const int pbase = pb2 * 64 + ii * 16 + q * 4;
    f32x4 zs = *(const f32x4*)&ze_sq[pbase];
    f32x4 zn = *(const f32x4*)&ze_norm[pbase];
    float m1r[4], m2r[4]; int k1r[4];
    #pragma unroll
    for (int r = 0; r < 4; ++r) { m1r[r] = 1e30f; m2r[r] = 1e30f; k1r[r] = 0; }
    #pragma unroll
    for (int j = 0; j < 4; ++j) {
      #pragma unroll
      for (int r = 0; r < 4; ++r) {
        float dsq = fmaxf(zs[r] + qsq_l[j] - 2.0f * acc[ii][j][r], 0.0f);
        float den = zn[r] + qn_l[j];
        float rd  = __builtin_amdgcn_rcpf(den);
        float m   = dsq * rd * rd;
        bool take = m < m1r[r];
        float loser = take ? m1r[r] : m;
        if (take) { m1r[r] = m; k1r[r] = kg[j]; }
        m2r[r] = fminf(m2r[r], loser);
      }
    }
    #pragma unroll
    for (int ms = 1; ms <= 8; ms <<= 1) {
      #pragma unroll
      for (int r = 0; r < 4; ++r) {
        float om1 = __shfl_xor(m1r[r], ms);
        int   ok1 = __shfl_xor(k1r[r], ms);
        float om2 = __shfl_xor(m2r[r], ms);
        bool take = (om1 < m1r[r]) || (om1 == m1r[r] && ok1 < k1r[r]);
        float loser = take ? m1r[r] : om1;
        if (take) { m1r[r] = om1; k1r[r] = ok1; }
        m2r[r] = fminf(fminf(m2r[r], om2), loser);
      }
    }
    if (col == 0) {
      const size_t o = (size_t)g * P_ + pbase;
      *(float4*)&val1[o] = make_float4(m1r[0], m1r[1], m1r[2], m1r[3]);
      *(int4*)&idx1[o]   = make_int4(k1r[0], k1r[1], k1r[2], k1r[3]);
      *(float4*)&val2[o] = make_float4(m2r[0], m2r[1], m2r[2], m2r[3]);
    }
  }
}

// ---- resolve 16 partials -> kstar; rank unflagged; flag ambiguous ----
__global__ __launch_bounds__(256) void resolve_kernel(
    const float* __restrict__ val1, const int* __restrict__ idx1,
    const float* __restrict__ val2, int* __restrict__ kstar,
    int* __restrict__ rank, int* __restrict__ counts,
    int* __restrict__ flaglist, int* __restrict__ flagcnt)
{
  const int p = blockIdx.x * 256 + threadIdx.x;
  float m1 = 1e30f, m2 = 1e30f; int k1 = 0;
  #pragma unroll
  for (int g = 0; g < 16; ++g) {        // g ascending == codes ascending
    float v1 = val1[(size_t)g * P_ + p];
    int   i1 = idx1[(size_t)g * P_ + p];
    float v2 = val2[(size_t)g * P_ + p];
    bool take = v1 < m1;
    float loser = take ? m1 : v1;
    if (take) { m1 = v1; k1 = i1; }
    m2 = fminf(fminf(m2, v2), loser);
  }
  kstar[p] = k1;
  if (m2 - m1 <= MARGIN_M) {
    int s = atomicAdd(flagcnt, 1);
    flaglist[s] = p;                    // ranked later by fallback
  } else {
    rank[p] = atomicAdd(&counts[k1], 1);
  }
}

// ---- exact fp32 rescan, BLOCK-parallel: 4 waves per flagged position.
// Wave w covers codes [256w,256w+256) in 4 lane-parallel tiles; dot is the
// validated single serial fmaf chain (same rounding as rounds 4-6). ----
__global__ __launch_bounds__(256) void fallback_kernel(
    const float* __restrict__ ze_pm, const float* __restrict__ emb,
    const float* __restrict__ ze_sq, const float* __restrict__ ze_norm,
    const float* __restrict__ q_sq, const float* __restrict__ q_norm,
    const int* __restrict__ flaglist, const int* __restrict__ flagcnt,
    int* __restrict__ kstar, int* __restrict__ rank, int* __restrict__ counts)
{
  __shared__ float zlds[128];
  __shared__ float wbs[4];
  __shared__ int   wbk[4];
  const int tid  = threadIdx.x;
  const int lane = tid & 63;
  const int w    = tid >> 6;            // 0..3
  const int cnt  = *flagcnt;
  for (int i = blockIdx.x; i < cnt; i += gridDim.x) {
    const int p = flaglist[i];
    __syncthreads();                    // protect zlds/wbs reuse
    if (tid < 128) zlds[tid] = ze_pm[(size_t)p * D_ + tid];
    __syncthreads();
    const float zsq = ze_sq[p], zn = ze_norm[p];
    float bs = 1e30f; int bk = 0;
    #pragma unroll
    for (int tt = 0; tt < 4; ++tt) {
      const int k = (w * 4 + tt) * 64 + lane;     // ascending per lane
      const float* e = emb + (size_t)k * D_;
      float dot = 0.f;
      #pragma unroll 8
      for (int d = 0; d < D_; ++d)
        dot = fmaf(zlds[d], e[d], dot);           // LDS broadcast + v-load
      float dsq = fmaxf(fmaf(-2.0f, dot, zsq + q_sq[k]), 0.0f);
      float sn  = sqrtf(dsq) / (zn + q_norm[k]);
      if (sn < bs) { bs = sn; bk = k; }
    }
    #pragma unroll
    for (int m = 1; m <= 32; m <<= 1) {           // 64-lane, lower-k ties
      float ov = __shfl_xor(bs, m);
      int   ok = __shfl_xor(bk, m);
      if (ov < bs || (ov == bs && ok < bk)) { bs = ov; bk = ok; }
    }
    if (lane == 0) { wbs[w] = bs; wbk[w] = bk; }
    __syncthreads();
    if (tid == 0) {
      float fb = wbs[0]; int fk = wbk[0];
      #pragma unroll
      for (int ww = 1; ww < 4; ++ww) {            // ascending k-ranges
        if (wbs[ww] < fb) { fb = wbs[ww]; fk = wbk[ww]; }
      }
      kstar[p] = fk;
      rank[p] = atomicAdd(&counts[fk], 1);
    }
  }
}

__global__ __launch_bounds__(1024) void prefix_kernel(
    const int* __restrict__ counts, const float* __restrict__ ema_denom,
    int* __restrict__ offsets, float* __restrict__ out_den)
{
  __shared__ int s[1024];
  const int t = threadIdx.x;
  const int c = counts[t];
  s[t] = c;
  __syncthreads();
  for (int off = 1; off < 1024; off <<= 1) {
    int v = (t >= off) ? s[t - off] : 0;
    __syncthreads();
    s[t] += v;
    __syncthreads();
  }
  offsets[t] = s[t] - c;
  out_den[t] = 0.99f * ema_denom[t] + 0.01f * (float)c;
}

__global__ __launch_bounds__(256) void scatter_kernel(
    const int* __restrict__ kstar, const int* __restrict__ rank,
    const int* __restrict__ offsets, int* __restrict__ pos_list,
    int* __restrict__ k_list)
{
  const int p = blockIdx.x * 256 + threadIdx.x;
  const int k = kstar[p];
  const int slot = offsets[k] + rank[p];
  pos_list[slot] = p;
  k_list[slot] = k;
}

__global__ __launch_bounds__(512) void zq_kernel(
    const float* __restrict__ ze_pm, const float* __restrict__ emb,
    const int* __restrict__ kstar, float* __restrict__ out)
{
  const int tid = threadIdx.x;
  const int lane = tid & 63;
  const int w = __builtin_amdgcn_readfirstlane(tid >> 6);
  const int p = blockIdx.x * 64 + lane;
  const int b = p >> 12;
  const int n = p & (N_ - 1);
  const int kst = kstar[p];
  const float* zr = ze_pm + (size_t)p * D_ + w * 16;
  const float* ek = emb + (size_t)kst * D_ + w * 16;
  float* op = out + (size_t)b * D_ * N_ + (size_t)(w * 16) * N_ + n;
  float4 zv[4], ev[4];
  #pragma unroll
  for (int r = 0; r < 4; ++r) {
    zv[r] = *(const float4*)&zr[r * 4];
    ev[r] = *(const float4*)&ek[r * 4];
  }
  #pragma unroll
  for (int r = 0; r < 4; ++r) {
    const float* zc = (const float*)&zv[r];
    const float* ec = (const float*)&ev[r];
    #pragma unroll
    for (int jj = 0; jj < 4; ++jj) {
      float zev = zc[jj];
      op[(size_t)(r * 4 + jj) * N_] = zev + (ec[jj] - zev);  // ref order
    }
  }
}

__global__ __launch_bounds__(128) void gsum_kernel(
    const float* __restrict__ ze_pm, const int* __restrict__ pos_list,
    const int* __restrict__ k_list, float* __restrict__ z_sum)
{
  const int d  = threadIdx.x;
  const int i0 = blockIdx.x * 32;
  int   kprev = -1;
  float acc = 0.f;
  #pragma unroll
  for (int ii = 0; ii < 32; ++ii) {
    int p = pos_list[i0 + ii];
    int k = k_list[i0 + ii];
    if (k != kprev) {
      if (kprev >= 0) atomicAdd(&z_sum[(size_t)kprev * D_ + d], acc);
      acc = 0.f;
      kprev = k;
    }
    acc += ze_pm[(size_t)p * D_ + d];
  }
  if (kprev >= 0) atomicAdd(&z_sum[(size_t)kprev * D_ + d], acc);
}

__global__ __launch_bounds__(256) void finalize_num_kernel(
    const float* __restrict__ ema_numer, const float* __restrict__ z_sum,
    float* __restrict__ out)
{
  const int t = blockIdx.x * 256 + threadIdx.x;
  float* out_num = out + (size_t)B_ * D_ * N_;
  out_num[t] = 0.99f * ema_numer[t] + 0.01f * z_sum[t];
}

extern "C" void kernel_launch(void* const* d_in, const int* in_sizes, int n_in,
                              void* d_out, int out_size, void* d_ws, size_t ws_size,
                              hipStream_t stream)
{
  (void)in_sizes; (void)n_in; (void)out_size; (void)ws_size;
  const float* z         = (const float*)d_in[0];
  const float* W         = (const float*)d_in[1];
  const float* emb       = (const float*)d_in[2];
  const float* ema_numer = (const float*)d_in[3];
  const float* ema_denom = (const float*)d_in[4];
  float* out = (float*)d_out;
  char*  ws  = (char*)d_ws;
  float* z_sum   = (float*)(ws + WS_ZSUM);
  int*   counts  = (int*)(ws + WS_CNT);
  int*   flagcnt = (int*)(ws + WS_FLAGC);
  int*   offsets = (int*)(ws + WS_OFF);
  float* q_sq    = (float*)(ws + WS_QSQ);
  float* q_norm  = (float*)(ws + WS_QNORM);
  int*   kstar   = (int*)(ws + WS_KSTAR);
  int*   rank    = (int*)(ws + WS_RANK);
  int*   plist   = (int*)(ws + WS_PLIST);
  int*   klist   = (int*)(ws + WS_KLIST);
  int*   flist   = (int*)(ws + WS_FLIST);
  float* Wt      = (float*)(ws + WS_WT);
  float* ze_pm   = (float*)(ws + WS_ZPM);
  float* ze_sq   = (float*)(ws + WS_ZESQ);
  float* ze_norm = (float*)(ws + WS_ZEN);
  uint4* ze2f    = (uint4*)(ws + WS_ZE2F);
  uint4* emb2f   = (uint4*)(ws + WS_EMB2F);
  float* val1    = (float*)(ws + WS_VAL1);
  int*   idx1    = (int*)(ws + WS_IDX1);
  float* val2    = (float*)(ws + WS_VAL2);
  float* out_den = out + (size_t)B_ * D_ * N_ + K_ * D_;

  hipMemsetAsync(ws, 0, WS_MEMSET, stream);   // z_sum + counts + flagcnt

  prep_kernel<<<196, 256, 0, stream>>>(W, emb, Wt, q_sq, q_norm, emb2f);
  ze_kernel<<<P_ / 64, 512, 0, stream>>>(z, Wt, ze_pm, ze_sq, ze_norm, ze2f);
  mfma_argmin_kernel<<<2048, 256, 0, stream>>>(ze2f, emb2f, ze_sq, ze_norm,
                                               q_sq, q_norm, val1, idx1, val2);
  resolve_kernel<<<P_ / 256, 256, 0, stream>>>(val1, idx1, val2, kstar,
                                               rank, counts, flist, flagcnt);
  fallback_kernel<<<1024, 256, 0, stream>>>(ze_pm, emb, ze_sq, ze_norm,
                                            q_sq, q_norm, flist, flagcnt,
                                            kstar, rank, counts);
  prefix_kernel<<<1, 1024, 0, stream>>>(counts, ema_denom, offsets, out_den);
  scatter_kernel<<<P_ / 256, 256, 0, stream>>>(kstar, rank, offsets, plist, klist);
  zq_kernel<<<P_ / 64, 512, 0, stream>>>(ze_pm, emb, kstar, out);
  gsum_kernel<<<P_ / 32, 128, 0, stream>>>(ze_pm, plist, klist, z_sum);
  finalize_num_kernel<<<K_ * D_ / 256, 256, 0, stream>>>(ema_numer, z_sum, out);
}

// Round 2
// 250.606 us; speedup vs baseline: 1.0475x; 1.0141x over previous
//
#include <hip/hip_runtime.h>
#include <cmath>
#include <stdint.h>

#define B_    8
#define NIN_  256
#define D_    128
#define K_    1024
#define N_    4096
#define P_    (B_ * N_)          // 32768 positions
#define MARGIN_M 1e-4f           // screening margin in m = dsq/den^2 domain

typedef __attribute__((ext_vector_type(8))) short bf16x8;   // 8 bf16 (4 VGPRs)
typedef __attribute__((ext_vector_type(4))) float f32x4;    // 4 fp32 acc

// ---- workspace layout (bytes), ~51 MB ----
#define WS_ZSUM   0                 // K*D*4 = 524288 (zeroed)
#define WS_CNT    524288            // 4096           (zeroed)
#define WS_FLAGC  528384            // 4096           (zeroed)
#define WS_MEMSET 532480
#define WS_OFF    532480
#define WS_QSQ    536576
#define WS_QNORM  540672
#define WS_KSTAR  544768            // P*4
#define WS_RANK   675840
#define WS_PLIST  806912
#define WS_KLIST  937984
#define WS_FLIST  1069056
#define WS_WT     1200128           // NIN*D*4
#define WS_ZPM    1331200           // P*D*4 = 16 MiB (p-major fp32 ze)
#define WS_ZESQ   18108416          // P*4
#define WS_ZEN    18239488          // P*4
#define WS_ZE2F   18370560          // 2048 pt x 12 c x 64 lane x 16B = 24 MiB
#define WS_EMB2F  43536384          // 64 kt x 12 x 64 x 16B = 768 KiB
#define WS_VAL1   44322816          // 16*P*4 = 2 MiB
#define WS_IDX1   46419968          // 2 MiB
#define WS_VAL2   48517120          // 2 MiB

__device__ inline unsigned short f2bf(float v) {          // RTNE fp32->bf16
  union { float f; uint32_t u; } c; c.f = v;
  return (unsigned short)((c.u + 0x7FFFu + ((c.u >> 16) & 1u)) >> 16);
}
__device__ inline float bf2f(unsigned short b) {
  union { float f; uint32_t u; } c; c.u = ((uint32_t)b) << 16; return c.f;
}
__device__ inline uint32_t pack2(float a, float b, int lo) {
  unsigned short ha = f2bf(a); if (lo) ha = f2bf(a - bf2f(ha));
  unsigned short hb = f2bf(b); if (lo) hb = f2bf(b - bf2f(hb));
  return (uint32_t)ha | ((uint32_t)hb << 16);
}

// ---- prep: Wt transpose, q_sq/q_norm, emb2f B-fragments, ws zeroing ----
__global__ __launch_bounds__(256) void prep_kernel(
    const float* __restrict__ W, const float* __restrict__ emb,
    float* __restrict__ Wt, float* __restrict__ q_sq, float* __restrict__ q_norm,
    uint4* __restrict__ emb2f, uint4* __restrict__ wszero)
{
  const int tid = threadIdx.x;
  const int bid = blockIdx.x;
  if (bid < 128) {
    int t = bid * 256 + tid;
    int c = t >> 7, d = t & 127;
    Wt[t] = W[d * NIN_ + c];
  } else if (bid < 132) {
    int k = (bid - 128) * 256 + tid;
    const float* e = emb + (size_t)k * D_;
    float s = 0.f;
    #pragma unroll 8
    for (int d = 0; d < D_; ++d) s = fmaf(e[d], e[d], s);
    q_sq[k] = s;
    q_norm[k] = sqrtf(s);
  } else if (bid < 196) {
    const int kt = bid - 132;             // 0..63
    #pragma unroll
    for (int i = 0; i < 3; ++i) {
      int f    = i * 256 + tid;           // 0..767
      int c    = f >> 6;
      int lane = f & 63;
      int k    = kt * 16 + (lane & 15);
      int q    = lane >> 4;
      int kk0  = c * 32 + q * 8;
      int lo   = (kk0 >> 7) == 1;
      int d0   = kk0 & 127;
      float4 v0 = *(const float4*)&emb[(size_t)k * D_ + d0];
      float4 v1 = *(const float4*)&emb[(size_t)k * D_ + d0 + 4];
      uint4 u;
      u.x = pack2(v0.x, v0.y, lo);
      u.y = pack2(v0.z, v0.w, lo);
      u.z = pack2(v1.x, v1.y, lo);
      u.w = pack2(v1.z, v1.w, lo);
      emb2f[(size_t)kt * 768 + f] = u;
    }
  } else {
    // zero z_sum + counts + flagcnt: 532480 B = 33280 uint4 = 130 blocks
    int t = (bid - 196) * 256 + tid;
    wszero[t] = make_uint4(0u, 0u, 0u, 0u);
  }
}

// ---- ze = W @ z: p-major fp32, ze_sq/ze_norm, ze2f A-fragments ----
__global__ __launch_bounds__(512) void ze_kernel(
    const float* __restrict__ z, const float* __restrict__ Wt,
    float* __restrict__ ze_pm, float* __restrict__ ze_sq,
    float* __restrict__ ze_norm, uint4* __restrict__ ze2f)
{
  __shared__ float tile[64][132];     // +4 pad
  __shared__ float sqpart[8][64];
  const int t    = threadIdx.x;
  const int lane = t & 63;
  const int wv   = __builtin_amdgcn_readfirstlane(t >> 6);   // 0..7
  const int p    = blockIdx.x * 64 + lane;
  const int b    = p >> 12;
  const int n    = p & (N_ - 1);

  float acc[16];
  #pragma unroll
  for (int j = 0; j < 16; ++j) acc[j] = 0.f;
  const float* zp = z + (size_t)b * NIN_ * N_ + n;
  const float* wp = Wt + wv * 16;
  #pragma unroll 4
  for (int c = 0; c < NIN_; ++c) {
    float zv = zp[(size_t)c * N_];                 // coalesced v-load
    #pragma unroll
    for (int j = 0; j < 16; ++j)
      acc[j] = fmaf(wp[c * D_ + j], zv, acc[j]);   // wave-uniform -> s_load
  }
  #pragma unroll
  for (int j = 0; j < 16; ++j) tile[lane][wv * 16 + j] = acc[j];
  float s = 0.f;
  #pragma unroll
  for (int j = 0; j < 16; ++j) s = fmaf(acc[j], acc[j], s);
  sqpart[wv][lane] = s;
  __syncthreads();
  if (wv == 0) {                        // same sum order as round 4 (passed)
    float tt = sqpart[0][lane];
    #pragma unroll
    for (int w = 1; w < 8; ++w) tt += sqpart[w][lane];
    ze_sq[p] = tt;
    ze_norm[p] = sqrtf(tt);
  }
  // p-major fp32 store via LDS transpose
  const int row = t >> 5;               // 0..15
  const int c4  = (t & 31) * 4;         // 0..124
  #pragma unroll
  for (int r = 0; r < 4; ++r) {
    int pr = r * 16 + row;
    float4 v = *(const float4*)&tile[pr][c4];
    *(float4*)&ze_pm[(size_t)(blockIdx.x * 64 + pr) * D_ + c4] = v;
  }
  // ze2f A-fragments: 4 pos-tiles x 768 frags = 3072, 6/thread, vectorized
  #pragma unroll
  for (int i = 0; i < 6; ++i) {
    int f    = i * 512 + t;             // 0..3071
    int lane_f = f & 63;
    int g    = f >> 6;                  // 0..47 = lpt*12 + c
    int c    = g % 12;
    int lpt  = g / 12;
    int pl   = lpt * 16 + (lane_f & 15);
    int q    = lane_f >> 4;
    int kk0  = c * 32 + q * 8;
    int lo   = (kk0 >> 7) == 2;
    int d0   = kk0 & 127;
    float4 v0 = *(const float4*)&tile[pl][d0];
    float4 v1 = *(const float4*)&tile[pl][d0 + 4];
    uint4 u;
    u.x = pack2(v0.x, v0.y, lo);
    u.y = pack2(v0.z, v0.w, lo);
    u.z = pack2(v1.x, v1.y, lo);
    u.w = pack2(v1.z, v1.w, lo);
    ze2f[((size_t)(blockIdx.x * 4 + lpt) * 12 + c) * 64 + lane_f] = u;
  }
}

// ---- MFMA GEMM-argmin, barrier-free direct-load, FORCED register pipeline.
// Same math/layout/grid as round 1; the c-loop is macro-unrolled over
// compile-time-indexed named buffers so the 8 prefetch loads per step stay
// in registers and in flight (round 1's VGPR_Count=72 showed the compiler
// demoted the runtime-parity double buffer; rule #20).
__global__ __launch_bounds__(256, 3) void mfma_argmin_kernel(
    const uint4* __restrict__ ze2f, const uint4* __restrict__ emb2f,
    const float* __restrict__ ze_sq, const float* __restrict__ ze_norm,
    const float* __restrict__ q_sq, const float* __restrict__ q_norm,
    float* __restrict__ val1, int* __restrict__ idx1, float* __restrict__ val2)
{
  const int tid  = threadIdx.x;
  const int lane = tid & 63;
  const int w    = __builtin_amdgcn_readfirstlane(tid >> 6);  // 0..3
  const int x    = blockIdx.x & 7;          // XCD slice
  const int ib   = blockIdx.x >> 3;         // 0..255 within XCD
  const int pb2  = x * 64 + (ib & 63);      // pos-block of 64   (0..511)
  const int kbb  = (ib >> 6) * 4 + w;       // code-block of 64  (0..15)

  // frag (pt,c) at ze2f[(pt*12+c)*64+lane]; pt = pb2*4+ii
  const uint4* a_base = ze2f  + (size_t)pb2 * 3072 + lane;
  // frag (ct,c) at emb2f[ct*768 + c*64 + lane]; ct = kbb*4+jj
  const uint4* b_base = emb2f + (size_t)kbb * 3072 + lane;

  f32x4 acc[4][4];
  #pragma unroll
  for (int ii = 0; ii < 4; ++ii)
    #pragma unroll
    for (int jj = 0; jj < 4; ++jj) acc[ii][jj] = (f32x4){0.f, 0.f, 0.f, 0.f};

  uint4 A0, A1, A2, A3, B0, B1, B2, B3;         // current step fragments
  uint4 nA0, nA1, nA2, nA3, nB0, nB1, nB2, nB3; // prefetch (step c+1)

  A0 = a_base[0 * 768]; A1 = a_base[1 * 768];
  A2 = a_base[2 * 768]; A3 = a_base[3 * 768];
  B0 = b_base[0 * 768]; B1 = b_base[1 * 768];
  B2 = b_base[2 * 768]; B3 = b_base[3 * 768];

#define MFMA16()                                                            \
  {                                                                         \
    union { uint4 u; bf16x8 h; } au0, au1, au2, au3, bu0, bu1, bu2, bu3;    \
    au0.u = A0; au1.u = A1; au2.u = A2; au3.u = A3;                         \
    bu0.u = B0; bu1.u = B1; bu2.u = B2; bu3.u = B3;                         \
    acc[0][0] = __builtin_amdgcn_mfma_f32_16x16x32_bf16(au0.h, bu0.h, acc[0][0], 0, 0, 0); \
    acc[0][1] = __builtin_amdgcn_mfma_f32_16x16x32_bf16(au0.h, bu1.h, acc[0][1], 0, 0, 0); \
    acc[0][2] = __builtin_amdgcn_mfma_f32_16x16x32_bf16(au0.h, bu2.h, acc[0][2], 0, 0, 0); \
    acc[0][3] = __builtin_amdgcn_mfma_f32_16x16x32_bf16(au0.h, bu3.h, acc[0][3], 0, 0, 0); \
    acc[1][0] = __builtin_amdgcn_mfma_f32_16x16x32_bf16(au1.h, bu0.h, acc[1][0], 0, 0, 0); \
    acc[1][1] = __builtin_amdgcn_mfma_f32_16x16x32_bf16(au1.h, bu1.h, acc[1][1], 0, 0, 0); \
    acc[1][2] = __builtin_amdgcn_mfma_f32_16x16x32_bf16(au1.h, bu2.h, acc[1][2], 0, 0, 0); \
    acc[1][3] = __builtin_amdgcn_mfma_f32_16x16x32_bf16(au1.h, bu3.h, acc[1][3], 0, 0, 0); \
    acc[2][0] = __builtin_amdgcn_mfma_f32_16x16x32_bf16(au2.h, bu0.h, acc[2][0], 0, 0, 0); \
    acc[2][1] = __builtin_amdgcn_mfma_f32_16x16x32_bf16(au2.h, bu1.h, acc[2][1], 0, 0, 0); \
    acc[2][2] = __builtin_amdgcn_mfma_f32_16x16x32_bf16(au2.h, bu2.h, acc[2][2], 0, 0, 0); \
    acc[2][3] = __builtin_amdgcn_mfma_f32_16x16x32_bf16(au2.h, bu3.h, acc[2][3], 0, 0, 0); \
    acc[3][0] = __builtin_amdgcn_mfma_f32_16x16x32_bf16(au3.h, bu0.h, acc[3][0], 0, 0, 0); \
    acc[3][1] = __builtin_amdgcn_mfma_f32_16x16x32_bf16(au3.h, bu1.h, acc[3][1], 0, 0, 0); \
    acc[3][2] = __builtin_amdgcn_mfma_f32_16x16x32_bf16(au3.h, bu2.h, acc[3][2], 0, 0, 0); \
    acc[3][3] = __builtin_amdgcn_mfma_f32_16x16x32_bf16(au3.h, bu3.h, acc[3][3], 0, 0, 0); \
  }

#define MSTEP(C)                                                            \
  {                                                                         \
    nA0 = a_base[0 * 768 + ((C) + 1) * 64];                                 \
    nA1 = a_base[1 * 768 + ((C) + 1) * 64];                                 \
    nA2 = a_base[2 * 768 + ((C) + 1) * 64];                                 \
    nA3 = a_base[3 * 768 + ((C) + 1) * 64];                                 \
    nB0 = b_base[0 * 768 + ((C) + 1) * 64];                                 \
    nB1 = b_base[1 * 768 + ((C) + 1) * 64];                                 \
    nB2 = b_base[2 * 768 + ((C) + 1) * 64];                                 \
    nB3 = b_base[3 * 768 + ((C) + 1) * 64];                                 \
    MFMA16();                                                               \
    A0 = nA0; A1 = nA1; A2 = nA2; A3 = nA3;                                 \
    B0 = nB0; B1 = nB1; B2 = nB2; B3 = nB3;                                 \
  }

  MSTEP(0) MSTEP(1) MSTEP(2) MSTEP(3) MSTEP(4) MSTEP(5)
  MSTEP(6) MSTEP(7) MSTEP(8) MSTEP(9) MSTEP(10)
  MFMA16()                                   // step 11, no prefetch

#undef MSTEP
#undef MFMA16

  // ---- epilogue: identical math/order to previous round ----
  const int col = lane & 15;
  const int q   = lane >> 4;
  float qsq_l[4], qn_l[4]; int kg[4];
  #pragma unroll
  for (int j = 0; j < 4; ++j) {
    kg[j]    = kbb * 64 + j * 16 + col;
    qsq_l[j] = q_sq[kg[j]];
    qn_l[j]  = q_norm[kg[j]];
  }
  const int g = kbb;
  #pragma unroll
  for (int ii = 0; ii < 4; ++ii) {
    const int pbase = pb2 * 64 + ii * 16 + q * 4;
    f32x4 zs = *(const f32x4*)&ze_sq[pbase];
    f32x4 zn = *(const f32x4*)&ze_norm[pbase];
    float m1r[4], m2r[4]; int k1r[4];
    #pragma unroll
    for (int r = 0; r < 4; ++r) { m1r[r] = 1e30f; m2r[r] = 1e30f; k1r[r] = 0; }
    #pragma unroll
    for (int j = 0; j < 4; ++j) {
      #pragma unroll
      for (int r = 0; r < 4; ++r) {
        float dsq = fmaxf(zs[r] + qsq_l[j] - 2.0f * acc[ii][j][r], 0.0f);
        float den = zn[r] + qn_l[j];
        float rd  = __builtin_amdgcn_rcpf(den);
        float m   = dsq * rd * rd;
        bool take = m < m1r[r];
        float loser = take ? m1r[r] : m;
        if (take) { m1r[r] = m; k1r[r] = kg[j]; }
        m2r[r] = fminf(m2r[r], loser);
      }
    }
    #pragma unroll
    for (int ms = 1; ms <= 8; ms <<= 1) {
      #pragma unroll
      for (int r = 0; r < 4; ++r) {
        float om1 = __shfl_xor(m1r[r], ms);
        int   ok1 = __shfl_xor(k1r[r], ms);
        float om2 = __shfl_xor(m2r[r], ms);
        bool take = (om1 < m1r[r]) || (om1 == m1r[r] && ok1 < k1r[r]);
        float loser = take ? m1r[r] : om1;
        if (take) { m1r[r] = om1; k1r[r] = ok1; }
        m2r[r] = fminf(fminf(m2r[r], om2), loser);
      }
    }
    if (col == 0) {
      const size_t o = (size_t)g * P_ + pbase;
      *(float4*)&val1[o] = make_float4(m1r[0], m1r[1], m1r[2], m1r[3]);
      *(int4*)&idx1[o]   = make_int4(k1r[0], k1r[1], k1r[2], k1r[3]);
      *(float4*)&val2[o] = make_float4(m2r[0], m2r[1], m2r[2], m2r[3]);
    }
  }
}

// ---- resolve 16 partials -> kstar; rank unflagged; flag ambiguous ----
__global__ __launch_bounds__(256) void resolve_kernel(
    const float* __restrict__ val1, const int* __restrict__ idx1,
    const float* __restrict__ val2, int* __restrict__ kstar,
    int* __restrict__ rank, int* __restrict__ counts,
    int* __restrict__ flaglist, int* __restrict__ flagcnt)
{
  const int p = blockIdx.x * 256 + threadIdx.x;
  float m1 = 1e30f, m2 = 1e30f; int k1 = 0;
  #pragma unroll
  for (int g = 0; g < 16; ++g) {        // g ascending == codes ascending
    float v1 = val1[(size_t)g * P_ + p];
    int   i1 = idx1[(size_t)g * P_ + p];
    float v2 = val2[(size_t)g * P_ + p];
    bool take = v1 < m1;
    float loser = take ? m1 : v1;
    if (take) { m1 = v1; k1 = i1; }
    m2 = fminf(fminf(m2, v2), loser);
  }
  kstar[p] = k1;
  if (m2 - m1 <= MARGIN_M) {
    int s = atomicAdd(flagcnt, 1);
    flaglist[s] = p;                    // ranked later by fallback
  } else {
    rank[p] = atomicAdd(&counts[k1], 1);
  }
}

// ---- exact fp32 rescan, BLOCK-parallel: 4 waves per flagged position.
// Wave w covers codes [256w,256w+256) in 4 lane-parallel tiles; dot is the
// validated single serial fmaf chain (same rounding as rounds 4-6). ----
__global__ __launch_bounds__(256) void fallback_kernel(
    const float* __restrict__ ze_pm, const float* __restrict__ emb,
    const float* __restrict__ ze_sq, const float* __restrict__ ze_norm,
    const float* __restrict__ q_sq, const float* __restrict__ q_norm,
    const int* __restrict__ flaglist, const int* __restrict__ flagcnt,
    int* __restrict__ kstar, int* __restrict__ rank, int* __restrict__ counts)
{
  __shared__ float zlds[128];
  __shared__ float wbs[4];
  __shared__ int   wbk[4];
  const int tid  = threadIdx.x;
  const int lane = tid & 63;
  const int w    = tid >> 6;            // 0..3
  const int cnt  = *flagcnt;
  for (int i = blockIdx.x; i < cnt; i += gridDim.x) {
    const int p = flaglist[i];
    __syncthreads();                    // protect zlds/wbs reuse
    if (tid < 128) zlds[tid] = ze_pm[(size_t)p * D_ + tid];
    __syncthreads();
    const float zsq = ze_sq[p], zn = ze_norm[p];
    float bs = 1e30f; int bk = 0;
    #pragma unroll
    for (int tt = 0; tt < 4; ++tt) {
      const int k = (w * 4 + tt) * 64 + lane;     // ascending per lane
      const float* e = emb + (size_t)k * D_;
      float dot = 0.f;
      #pragma unroll 8
      for (int d = 0; d < D_; ++d)
        dot = fmaf(zlds[d], e[d], dot);           // LDS broadcast + v-load
      float dsq = fmaxf(fmaf(-2.0f, dot, zsq + q_sq[k]), 0.0f);
      float sn  = sqrtf(dsq) / (zn + q_norm[k]);
      if (sn < bs) { bs = sn; bk = k; }
    }
    #pragma unroll
    for (int m = 1; m <= 32; m <<= 1) {           // 64-lane, lower-k ties
      float ov = __shfl_xor(bs, m);
      int   ok = __shfl_xor(bk, m);
      if (ov < bs || (ov == bs && ok < bk)) { bs = ov; bk = ok; }
    }
    if (lane == 0) { wbs[w] = bs; wbk[w] = bk; }
    __syncthreads();
    if (tid == 0) {
      float fb = wbs[0]; int fk = wbk[0];
      #pragma unroll
      for (int ww = 1; ww < 4; ++ww) {            // ascending k-ranges
        if (wbs[ww] < fb) { fb = wbs[ww]; fk = wbk[ww]; }
      }
      kstar[p] = fk;
      rank[p] = atomicAdd(&counts[fk], 1);
    }
  }
}

__global__ __launch_bounds__(1024) void prefix_kernel(
    const int* __restrict__ counts, const float* __restrict__ ema_denom,
    int* __restrict__ offsets, float* __restrict__ out_den)
{
  __shared__ int s[1024];
  const int t = threadIdx.x;
  const int c = counts[t];
  s[t] = c;
  __syncthreads();
  for (int off = 1; off < 1024; off <<= 1) {
    int v = (t >= off) ? s[t - off] : 0;
    __syncthreads();
    s[t] += v;
    __syncthreads();
  }
  offsets[t] = s[t] - c;
  out_den[t] = 0.99f * ema_denom[t] + 0.01f * (float)c;
}

__global__ __launch_bounds__(256) void scatter_kernel(
    const int* __restrict__ kstar, const int* __restrict__ rank,
    const int* __restrict__ offsets, int* __restrict__ pos_list,
    int* __restrict__ k_list)
{
  const int p = blockIdx.x * 256 + threadIdx.x;
  const int k = kstar[p];
  const int slot = offsets[k] + rank[p];
  pos_list[slot] = p;
  k_list[slot] = k;
}

__global__ __launch_bounds__(512) void zq_kernel(
    const float* __restrict__ ze_pm, const float* __restrict__ emb,
    const int* __restrict__ kstar, float* __restrict__ out)
{
  const int tid = threadIdx.x;
  const int lane = tid & 63;
  const int w = __builtin_amdgcn_readfirstlane(tid >> 6);
  const int p = blockIdx.x * 64 + lane;
  const int b = p >> 12;
  const int n = p & (N_ - 1);
  const int kst = kstar[p];
  const float* zr = ze_pm + (size_t)p * D_ + w * 16;
  const float* ek = emb + (size_t)kst * D_ + w * 16;
  float* op = out + (size_t)b * D_ * N_ + (size_t)(w * 16) * N_ + n;
  float4 zv[4], ev[4];
  #pragma unroll
  for (int r = 0; r < 4; ++r) {
    zv[r] = *(const float4*)&zr[r * 4];
    ev[r] = *(const float4*)&ek[r * 4];
  }
  #pragma unroll
  for (int r = 0; r < 4; ++r) {
    const float* zc = (const float*)&zv[r];
    const float* ec = (const float*)&ev[r];
    #pragma unroll
    for (int jj = 0; jj < 4; ++jj) {
      float zev = zc[jj];
      op[(size_t)(r * 4 + jj) * N_] = zev + (ec[jj] - zev);  // ref order
    }
  }
}

__global__ __launch_bounds__(128) void gsum_kernel(
    const float* __restrict__ ze_pm, const int* __restrict__ pos_list,
    const int* __restrict__ k_list, float* __restrict__ z_sum)
{
  const int d  = threadIdx.x;
  const int i0 = blockIdx.x * 32;
  int   kprev = -1;
  float acc = 0.f;
  #pragma unroll
  for (int ii = 0; ii < 32; ++ii) {
    int p = pos_list[i0 + ii];
    int k = k_list[i0 + ii];
    if (k != kprev) {
      if (kprev >= 0) atomicAdd(&z_sum[(size_t)kprev * D_ + d], acc);
      acc = 0.f;
      kprev = k;
    }
    acc += ze_pm[(size_t)p * D_ + d];
  }
  if (kprev >= 0) atomicAdd(&z_sum[(size_t)kprev * D_ + d], acc);
}

__global__ __launch_bounds__(256) void finalize_num_kernel(
    const float* __restrict__ ema_numer, const float* __restrict__ z_sum,
    float* __restrict__ out)
{
  const int t = blockIdx.x * 256 + threadIdx.x;
  float* out_num = out + (size_t)B_ * D_ * N_;
  out_num[t] = 0.99f * ema_numer[t] + 0.01f * z_sum[t];
}

extern "C" void kernel_launch(void* const* d_in, const int* in_sizes, int n_in,
                              void* d_out, int out_size, void* d_ws, size_t ws_size,
                              hipStream_t stream)
{
  (void)in_sizes; (void)n_in; (void)out_size; (void)ws_size;
  const float* z         = (const float*)d_in[0];
  const float* W         = (const float*)d_in[1];
  const float* emb       = (const float*)d_in[2];
  const float* ema_numer = (const float*)d_in[3];
  const float* ema_denom = (const float*)d_in[4];
  float* out = (float*)d_out;
  char*  ws  = (char*)d_ws;
  float* z_sum   = (float*)(ws + WS_ZSUM);
  int*   counts  = (int*)(ws + WS_CNT);
  int*   flagcnt = (int*)(ws + WS_FLAGC);
  int*   offsets = (int*)(ws + WS_OFF);
  float* q_sq    = (float*)(ws + WS_QSQ);
  float* q_norm  = (float*)(ws + WS_QNORM);
  int*   kstar   = (int*)(ws + WS_KSTAR);
  int*   rank    = (int*)(ws + WS_RANK);
  int*   plist   = (int*)(ws + WS_PLIST);
  int*   klist   = (int*)(ws + WS_KLIST);
  int*   flist   = (int*)(ws + WS_FLIST);
  float* Wt      = (float*)(ws + WS_WT);
  float* ze_pm   = (float*)(ws + WS_ZPM);
  float* ze_sq   = (float*)(ws + WS_ZESQ);
  float* ze_norm = (float*)(ws + WS_ZEN);
  uint4* ze2f    = (uint4*)(ws + WS_ZE2F);
  uint4* emb2f   = (uint4*)(ws + WS_EMB2F);
  float* val1    = (float*)(ws + WS_VAL1);
  int*   idx1    = (int*)(ws + WS_IDX1);
  float* val2    = (float*)(ws + WS_VAL2);
  float* out_den = out + (size_t)B_ * D_ * N_ + K_ * D_;

  // ws zeroing folded into prep_kernel (blocks 196..325)
  prep_kernel<<<326, 256, 0, stream>>>(W, emb, Wt, q_sq, q_norm, emb2f,
                                       (uint4*)ws);
  ze_kernel<<<P_ / 64, 512, 0, stream>>>(z, Wt, ze_pm, ze_sq, ze_norm, ze2f);
  mfma_argmin_kernel<<<2048, 256, 0, stream>>>(ze2f, emb2f, ze_sq, ze_norm,
                                               q_sq, q_norm, val1, idx1, val2);
  resolve_kernel<<<P_ / 256, 256, 0, stream>>>(val1, idx1, val2, kstar,
                                               rank, counts, flist, flagcnt);
  fallback_kernel<<<1024, 256, 0, stream>>>(ze_pm, emb, ze_sq, ze_norm,
                                            q_sq, q_norm, flist, flagcnt,
                                            kstar, rank, counts);
  prefix_kernel<<<1, 1024, 0, stream>>>(counts, ema_denom, offsets, out_den);
  scatter_kernel<<<P_ / 256, 256, 0, stream>>>(kstar, rank, offsets, plist, klist);
  zq_kernel<<<P_ / 64, 512, 0, stream>>>(ze_pm, emb, kstar, out);
  gsum_kernel<<<P_ / 32, 128, 0, stream>>>(ze_pm, plist, klist, z_sum);
  finalize_num_kernel<<<K_ * D_ / 256, 256, 0, stream>>>(ema_numer, z_sum, out);
}

// Round 3
// 239.088 us; speedup vs baseline: 1.0980x; 1.0482x over previous
//
#include <hip/hip_runtime.h>
#include <cmath>
#include <stdint.h>

#define B_    8
#define NIN_  256
#define D_    128
#define K_    1024
#define N_    4096
#define P_    (B_ * N_)          // 32768 positions
#define MARGIN_M 1e-4f           // screening margin in m = dsq/den^2 domain

typedef __attribute__((ext_vector_type(8))) short bf16x8;   // 8 bf16 (4 VGPRs)
typedef __attribute__((ext_vector_type(4))) float f32x4;    // 4 fp32 acc

// ---- workspace layout (bytes), ~51 MB ----
#define WS_ZSUM   0                 // K*D*4 = 524288 (zeroed)
#define WS_CNT    524288            // 4096           (zeroed)
#define WS_FLAGC  528384            // 4096           (zeroed)
#define WS_MEMSET 532480
#define WS_OFF    532480
#define WS_QSQ    536576
#define WS_QNORM  540672
#define WS_KSTAR  544768            // P*4
#define WS_RANK   675840
#define WS_PLIST  806912
#define WS_KLIST  937984
#define WS_FLIST  1069056
#define WS_WT     1200128           // NIN*D*4
#define WS_ZPM    1331200           // P*D*4 = 16 MiB (p-major fp32 ze)
#define WS_ZESQ   18108416          // P*4
#define WS_ZEN    18239488          // P*4
#define WS_ZE2F   18370560          // 2048 pt x 12 c x 64 lane x 16B = 24 MiB
#define WS_EMB2F  43536384          // 64 kt x 12 x 64 x 16B = 768 KiB
#define WS_VAL1   44322816          // 16*P*4 = 2 MiB
#define WS_IDX1   46419968          // 2 MiB
#define WS_VAL2   48517120          // 2 MiB

__device__ inline unsigned short f2bf(float v) {          // RTNE fp32->bf16
  union { float f; uint32_t u; } c; c.f = v;
  return (unsigned short)((c.u + 0x7FFFu + ((c.u >> 16) & 1u)) >> 16);
}
__device__ inline float bf2f(unsigned short b) {
  union { float f; uint32_t u; } c; c.u = ((uint32_t)b) << 16; return c.f;
}
__device__ inline uint32_t pack2(float a, float b, int lo) {
  unsigned short ha = f2bf(a); if (lo) ha = f2bf(a - bf2f(ha));
  unsigned short hb = f2bf(b); if (lo) hb = f2bf(b - bf2f(hb));
  return (uint32_t)ha | ((uint32_t)hb << 16);
}

// async global->LDS, 16B per lane; LDS dest is wave-uniform base + lane*16
__device__ inline void gl_lds(const uint4* g, uint4* l) {
  __builtin_amdgcn_global_load_lds(
      (const __attribute__((address_space(1))) unsigned int*)g,
      (__attribute__((address_space(3))) unsigned int*)l, 16, 0, 0);
}

// ---- prep: Wt transpose, q_sq/q_norm, emb2f B-fragments, ws zeroing ----
__global__ __launch_bounds__(256) void prep_kernel(
    const float* __restrict__ W, const float* __restrict__ emb,
    float* __restrict__ Wt, float* __restrict__ q_sq, float* __restrict__ q_norm,
    uint4* __restrict__ emb2f, uint4* __restrict__ wszero)
{
  const int tid = threadIdx.x;
  const int bid = blockIdx.x;
  if (bid < 128) {
    int t = bid * 256 + tid;
    int c = t >> 7, d = t & 127;
    Wt[t] = W[d * NIN_ + c];
  } else if (bid < 132) {
    int k = (bid - 128) * 256 + tid;
    const float* e = emb + (size_t)k * D_;
    float s = 0.f;
    #pragma unroll 8
    for (int d = 0; d < D_; ++d) s = fmaf(e[d], e[d], s);
    q_sq[k] = s;
    q_norm[k] = sqrtf(s);
  } else if (bid < 196) {
    const int kt = bid - 132;             // 0..63
    #pragma unroll
    for (int i = 0; i < 3; ++i) {
      int f    = i * 256 + tid;           // 0..767
      int c    = f >> 6;
      int lane = f & 63;
      int k    = kt * 16 + (lane & 15);
      int q    = lane >> 4;
      int kk0  = c * 32 + q * 8;
      int lo   = (kk0 >> 7) == 1;
      int d0   = kk0 & 127;
      float4 v0 = *(const float4*)&emb[(size_t)k * D_ + d0];
      float4 v1 = *(const float4*)&emb[(size_t)k * D_ + d0 + 4];
      uint4 u;
      u.x = pack2(v0.x, v0.y, lo);
      u.y = pack2(v0.z, v0.w, lo);
      u.z = pack2(v1.x, v1.y, lo);
      u.w = pack2(v1.z, v1.w, lo);
      emb2f[(size_t)kt * 768 + f] = u;
    }
  } else {
    // zero z_sum + counts + flagcnt: 532480 B = 33280 uint4 = 130 blocks
    int t = (bid - 196) * 256 + tid;
    wszero[t] = make_uint4(0u, 0u, 0u, 0u);
  }
}

// ---- ze = W @ z: p-major fp32, ze_sq/ze_norm, ze2f A-fragments ----
__global__ __launch_bounds__(512) void ze_kernel(
    const float* __restrict__ z, const float* __restrict__ Wt,
    float* __restrict__ ze_pm, float* __restrict__ ze_sq,
    float* __restrict__ ze_norm, uint4* __restrict__ ze2f)
{
  __shared__ float tile[64][132];     // +4 pad
  __shared__ float sqpart[8][64];
  const int t    = threadIdx.x;
  const int lane = t & 63;
  const int wv   = __builtin_amdgcn_readfirstlane(t >> 6);   // 0..7
  const int p    = blockIdx.x * 64 + lane;
  const int b    = p >> 12;
  const int n    = p & (N_ - 1);

  float acc[16];
  #pragma unroll
  for (int j = 0; j < 16; ++j) acc[j] = 0.f;
  const float* zp = z + (size_t)b * NIN_ * N_ + n;
  const float* wp = Wt + wv * 16;
  #pragma unroll 4
  for (int c = 0; c < NIN_; ++c) {
    float zv = zp[(size_t)c * N_];                 // coalesced v-load
    #pragma unroll
    for (int j = 0; j < 16; ++j)
      acc[j] = fmaf(wp[c * D_ + j], zv, acc[j]);   // wave-uniform -> s_load
  }
  #pragma unroll
  for (int j = 0; j < 16; ++j) tile[lane][wv * 16 + j] = acc[j];
  float s = 0.f;
  #pragma unroll
  for (int j = 0; j < 16; ++j) s = fmaf(acc[j], acc[j], s);
  sqpart[wv][lane] = s;
  __syncthreads();
  if (wv == 0) {                        // same sum order as round 4 (passed)
    float tt = sqpart[0][lane];
    #pragma unroll
    for (int w = 1; w < 8; ++w) tt += sqpart[w][lane];
    ze_sq[p] = tt;
    ze_norm[p] = sqrtf(tt);
  }
  // p-major fp32 store via LDS transpose
  const int row = t >> 5;               // 0..15
  const int c4  = (t & 31) * 4;         // 0..124
  #pragma unroll
  for (int r = 0; r < 4; ++r) {
    int pr = r * 16 + row;
    float4 v = *(const float4*)&tile[pr][c4];
    *(float4*)&ze_pm[(size_t)(blockIdx.x * 64 + pr) * D_ + c4] = v;
  }
  // ze2f A-fragments: 4 pos-tiles x 768 frags = 3072, 6/thread, vectorized
  #pragma unroll
  for (int i = 0; i < 6; ++i) {
    int f    = i * 512 + t;             // 0..3071
    int lane_f = f & 63;
    int g    = f >> 6;                  // 0..47 = lpt*12 + c
    int c    = g % 12;
    int lpt  = g / 12;
    int pl   = lpt * 16 + (lane_f & 15);
    int q    = lane_f >> 4;
    int kk0  = c * 32 + q * 8;
    int lo   = (kk0 >> 7) == 2;
    int d0   = kk0 & 127;
    float4 v0 = *(const float4*)&tile[pl][d0];
    float4 v1 = *(const float4*)&tile[pl][d0 + 4];
    uint4 u;
    u.x = pack2(v0.x, v0.y, lo);
    u.y = pack2(v0.z, v0.w, lo);
    u.z = pack2(v1.x, v1.y, lo);
    u.w = pack2(v1.z, v1.w, lo);
    ze2f[((size_t)(blockIdx.x * 4 + lpt) * 12 + c) * 64 + lane_f] = u;
  }
}

// ---- MFMA GEMM-argmin, LDS-shared 128x128 block tile, counted-vmcnt
// pipeline. 4 waves (2x2); 16 shared frags/step staged via global_load_lds
// (each frag = 64 lanes x 16B linear row -> wave-uniform dest constraint OK).
// L2 bytes/MFMA: 512 -> 256 (A shared 2x, B shared 2x within block).
// s_waitcnt vmcnt(4) mid-loop (never 0) so next-step loads stay in flight
// across barriers (T4). MFMA order per accumulator identical to rounds 1-2.
__global__ __launch_bounds__(256, 4) void mfma_argmin_kernel(
    const uint4* __restrict__ ze2f, const uint4* __restrict__ emb2f,
    const float* __restrict__ ze_sq, const float* __restrict__ ze_norm,
    const float* __restrict__ q_sq, const float* __restrict__ q_norm,
    float* __restrict__ val1, int* __restrict__ idx1, float* __restrict__ val2)
{
  __shared__ uint4 Ls[2][16][64];           // [buf][frag][lane], 32 KiB
  const int tid  = threadIdx.x;
  const int lane = tid & 63;
  const int w    = __builtin_amdgcn_readfirstlane(tid >> 6);  // 0..3
  const int x    = blockIdx.x & 7;          // XCD slice
  const int ib   = blockIdx.x >> 3;         // 0..255 within XCD
  const int pb3  = x * 32 + (ib & 31);      // 128-pos block (0..255)
  const int kb2  = ib >> 5;                 // 128-code block (0..7)
  const int pt0  = pb3 * 8;                 // first 16-pos tile
  const int ct0  = kb2 * 8;                 // first 16-code tile
  const int wm   = w >> 1;                  // pos half (0..1)
  const int wn   = w & 1;                   // code half (0..1)
  const int wq   = w * 4;                   // staged frag base for this wave
  const int wm4  = wm * 4;
  const int wn4  = wn * 4;

  // staging source: wave 0,1 -> A frags 0..7 (pos tiles pt0..pt0+7);
  //                 wave 2,3 -> B frags 8..15 (code tiles ct0..ct0+7)
  const uint4* sbase = (w < 2)
      ? ze2f  + ((size_t)(pt0 + w * 4) * 12) * 64 + lane
      : emb2f + ((size_t)(ct0 + (w - 2) * 4) * 12) * 64 + lane;

  f32x4 acc[4][4];
  #pragma unroll
  for (int ii = 0; ii < 4; ++ii)
    #pragma unroll
    for (int jj = 0; jj < 4; ++jj) acc[ii][jj] = (f32x4){0.f, 0.f, 0.f, 0.f};

#define STAGE(NB, C)                                                        \
  gl_lds(sbase + 0 * 768 + (C) * 64, &Ls[NB][wq + 0][0]);                   \
  gl_lds(sbase + 1 * 768 + (C) * 64, &Ls[NB][wq + 1][0]);                   \
  gl_lds(sbase + 2 * 768 + (C) * 64, &Ls[NB][wq + 2][0]);                   \
  gl_lds(sbase + 3 * 768 + (C) * 64, &Ls[NB][wq + 3][0]);

#define MFMA_STEP(CUR)                                                      \
  {                                                                         \
    uint4 afr[4], bfr[4];                                                   \
    afr[0] = Ls[CUR][wm4 + 0][lane];  afr[1] = Ls[CUR][wm4 + 1][lane];      \
    afr[2] = Ls[CUR][wm4 + 2][lane];  afr[3] = Ls[CUR][wm4 + 3][lane];      \
    bfr[0] = Ls[CUR][8 + wn4 + 0][lane]; bfr[1] = Ls[CUR][8 + wn4 + 1][lane]; \
    bfr[2] = Ls[CUR][8 + wn4 + 2][lane]; bfr[3] = Ls[CUR][8 + wn4 + 3][lane]; \
    __builtin_amdgcn_s_setprio(1);                                          \
    _Pragma("unroll")                                                       \
    for (int ii = 0; ii < 4; ++ii) {                                        \
      union { uint4 u; bf16x8 h; } au; au.u = afr[ii];                      \
      _Pragma("unroll")                                                     \
      for (int jj = 0; jj < 4; ++jj) {                                      \
        union { uint4 u; bf16x8 h; } bu; bu.u = bfr[jj];                    \
        acc[ii][jj] = __builtin_amdgcn_mfma_f32_16x16x32_bf16(au.h, bu.h,   \
                                                        acc[ii][jj], 0, 0, 0); \
      }                                                                     \
    }                                                                       \
    __builtin_amdgcn_s_setprio(0);                                          \
  }

#define STEP_MID(C, CUR, NXT)                                               \
  STAGE(NXT, (C) + 1)                                                       \
  asm volatile("s_waitcnt vmcnt(4)" ::: "memory");                          \
  __builtin_amdgcn_s_barrier();                                             \
  __builtin_amdgcn_sched_barrier(0);                                        \
  MFMA_STEP(CUR)                                                            \
  __builtin_amdgcn_s_barrier();                                             \
  __builtin_amdgcn_sched_barrier(0);

  STAGE(0, 0)
  STEP_MID(0, 0, 1)  STEP_MID(1, 1, 0)  STEP_MID(2, 0, 1)  STEP_MID(3, 1, 0)
  STEP_MID(4, 0, 1)  STEP_MID(5, 1, 0)  STEP_MID(6, 0, 1)  STEP_MID(7, 1, 0)
  STEP_MID(8, 0, 1)  STEP_MID(9, 1, 0)  STEP_MID(10, 0, 1)
  asm volatile("s_waitcnt vmcnt(0)" ::: "memory");
  __builtin_amdgcn_s_barrier();
  __builtin_amdgcn_sched_barrier(0);
  MFMA_STEP(1)                               // c = 11, buf 1, no prefetch

#undef STEP_MID
#undef MFMA_STEP
#undef STAGE

  // ---- epilogue: identical math/order to previous rounds ----
  const int col = lane & 15;
  const int q   = lane >> 4;
  float qsq_l[4], qn_l[4]; int kg[4];
  #pragma unroll
  for (int j = 0; j < 4; ++j) {
    kg[j]    = kb2 * 128 + wn * 64 + j * 16 + col;
    qsq_l[j] = q_sq[kg[j]];
    qn_l[j]  = q_norm[kg[j]];
  }
  const int g = kb2 * 2 + wn;               // 64-code output group (0..15)
  #pragma unroll
  for (int ii = 0; ii < 4; ++ii) {
    const int pbase = pb3 * 128 + wm * 64 + ii * 16 + q * 4;
    f32x4 zs = *(const f32x4*)&ze_sq[pbase];
    f32x4 zn = *(const f32x4*)&ze_norm[pbase];
    float m1r[4], m2r[4]; int k1r[4];
    #pragma unroll
    for (int r = 0; r < 4; ++r) { m1r[r] = 1e30f; m2r[r] = 1e30f; k1r[r] = 0; }
    #pragma unroll
    for (int j = 0; j < 4; ++j) {
      #pragma unroll
      for (int r = 0; r < 4; ++r) {
        float dsq = fmaxf(zs[r] + qsq_l[j] - 2.0f * acc[ii][j][r], 0.0f);
        float den = zn[r] + qn_l[j];
        float rd  = __builtin_amdgcn_rcpf(den);
        float m   = dsq * rd * rd;
        bool take = m < m1r[r];
        float loser = take ? m1r[r] : m;
        if (take) { m1r[r] = m; k1r[r] = kg[j]; }
        m2r[r] = fminf(m2r[r], loser);
      }
    }
    #pragma unroll
    for (int ms = 1; ms <= 8; ms <<= 1) {
      #pragma unroll
      for (int r = 0; r < 4; ++r) {
        float om1 = __shfl_xor(m1r[r], ms);
        int   ok1 = __shfl_xor(k1r[r], ms);
        float om2 = __shfl_xor(m2r[r], ms);
        bool take = (om1 < m1r[r]) || (om1 == m1r[r] && ok1 < k1r[r]);
        float loser = take ? m1r[r] : om1;
        if (take) { m1r[r] = om1; k1r[r] = ok1; }
        m2r[r] = fminf(fminf(m2r[r], om2), loser);
      }
    }
    if (col == 0) {
      const size_t o = (size_t)g * P_ + pbase;
      *(float4*)&val1[o] = make_float4(m1r[0], m1r[1], m1r[2], m1r[3]);
      *(int4*)&idx1[o]   = make_int4(k1r[0], k1r[1], k1r[2], k1r[3]);
      *(float4*)&val2[o] = make_float4(m2r[0], m2r[1], m2r[2], m2r[3]);
    }
  }
}

// ---- resolve 16 partials -> kstar; rank unflagged; flag ambiguous ----
__global__ __launch_bounds__(256) void resolve_kernel(
    const float* __restrict__ val1, const int* __restrict__ idx1,
    const float* __restrict__ val2, int* __restrict__ kstar,
    int* __restrict__ rank, int* __restrict__ counts,
    int* __restrict__ flaglist, int* __restrict__ flagcnt)
{
  const int p = blockIdx.x * 256 + threadIdx.x;
  float m1 = 1e30f, m2 = 1e30f; int k1 = 0;
  #pragma unroll
  for (int g = 0; g < 16; ++g) {        // g ascending == codes ascending
    float v1 = val1[(size_t)g * P_ + p];
    int   i1 = idx1[(size_t)g * P_ + p];
    float v2 = val2[(size_t)g * P_ + p];
    bool take = v1 < m1;
    float loser = take ? m1 : v1;
    if (take) { m1 = v1; k1 = i1; }
    m2 = fminf(fminf(m2, v2), loser);
  }
  kstar[p] = k1;
  if (m2 - m1 <= MARGIN_M) {
    int s = atomicAdd(flagcnt, 1);
    flaglist[s] = p;                    // ranked later by fallback
  } else {
    rank[p] = atomicAdd(&counts[k1], 1);
  }
}

// ---- exact fp32 rescan, BLOCK-parallel: 4 waves per flagged position.
// Wave w covers codes [256w,256w+256) in 4 lane-parallel tiles; dot is the
// validated single serial fmaf chain (same rounding as rounds 4-6). ----
__global__ __launch_bounds__(256) void fallback_kernel(
    const float* __restrict__ ze_pm, const float* __restrict__ emb,
    const float* __restrict__ ze_sq, const float* __restrict__ ze_norm,
    const float* __restrict__ q_sq, const float* __restrict__ q_norm,
    const int* __restrict__ flaglist, const int* __restrict__ flagcnt,
    int* __restrict__ kstar, int* __restrict__ rank, int* __restrict__ counts)
{
  __shared__ float zlds[128];
  __shared__ float wbs[4];
  __shared__ int   wbk[4];
  const int tid  = threadIdx.x;
  const int lane = tid & 63;
  const int w    = tid >> 6;            // 0..3
  const int cnt  = *flagcnt;
  for (int i = blockIdx.x; i < cnt; i += gridDim.x) {
    const int p = flaglist[i];
    __syncthreads();                    // protect zlds/wbs reuse
    if (tid < 128) zlds[tid] = ze_pm[(size_t)p * D_ + tid];
    __syncthreads();
    const float zsq = ze_sq[p], zn = ze_norm[p];
    float bs = 1e30f; int bk = 0;
    #pragma unroll
    for (int tt = 0; tt < 4; ++tt) {
      const int k = (w * 4 + tt) * 64 + lane;     // ascending per lane
      const float* e = emb + (size_t)k * D_;
      float dot = 0.f;
      #pragma unroll 8
      for (int d = 0; d < D_; ++d)
        dot = fmaf(zlds[d], e[d], dot);           // LDS broadcast + v-load
      float dsq = fmaxf(fmaf(-2.0f, dot, zsq + q_sq[k]), 0.0f);
      float sn  = sqrtf(dsq) / (zn + q_norm[k]);
      if (sn < bs) { bs = sn; bk = k; }
    }
    #pragma unroll
    for (int m = 1; m <= 32; m <<= 1) {           // 64-lane, lower-k ties
      float ov = __shfl_xor(bs, m);
      int   ok = __shfl_xor(bk, m);
      if (ov < bs || (ov == bs && ok < bk)) { bs = ov; bk = ok; }
    }
    if (lane == 0) { wbs[w] = bs; wbk[w] = bk; }
    __syncthreads();
    if (tid == 0) {
      float fb = wbs[0]; int fk = wbk[0];
      #pragma unroll
      for (int ww = 1; ww < 4; ++ww) {            // ascending k-ranges
        if (wbs[ww] < fb) { fb = wbs[ww]; fk = wbk[ww]; }
      }
      kstar[p] = fk;
      rank[p] = atomicAdd(&counts[fk], 1);
    }
  }
}

__global__ __launch_bounds__(1024) void prefix_kernel(
    const int* __restrict__ counts, const float* __restrict__ ema_denom,
    int* __restrict__ offsets, float* __restrict__ out_den)
{
  __shared__ int s[1024];
  const int t = threadIdx.x;
  const int c = counts[t];
  s[t] = c;
  __syncthreads();
  for (int off = 1; off < 1024; off <<= 1) {
    int v = (t >= off) ? s[t - off] : 0;
    __syncthreads();
    s[t] += v;
    __syncthreads();
  }
  offsets[t] = s[t] - c;
  out_den[t] = 0.99f * ema_denom[t] + 0.01f * (float)c;
}

__global__ __launch_bounds__(256) void scatter_kernel(
    const int* __restrict__ kstar, const int* __restrict__ rank,
    const int* __restrict__ offsets, int* __restrict__ pos_list,
    int* __restrict__ k_list)
{
  const int p = blockIdx.x * 256 + threadIdx.x;
  const int k = kstar[p];
  const int slot = offsets[k] + rank[p];
  pos_list[slot] = p;
  k_list[slot] = k;
}

__global__ __launch_bounds__(512) void zq_kernel(
    const float* __restrict__ ze_pm, const float* __restrict__ emb,
    const int* __restrict__ kstar, float* __restrict__ out)
{
  const int tid = threadIdx.x;
  const int lane = tid & 63;
  const int w = __builtin_amdgcn_readfirstlane(tid >> 6);
  const int p = blockIdx.x * 64 + lane;
  const int b = p >> 12;
  const int n = p & (N_ - 1);
  const int kst = kstar[p];
  const float* zr = ze_pm + (size_t)p * D_ + w * 16;
  const float* ek = emb + (size_t)kst * D_ + w * 16;
  float* op = out + (size_t)b * D_ * N_ + (size_t)(w * 16) * N_ + n;
  float4 zv[4], ev[4];
  #pragma unroll
  for (int r = 0; r < 4; ++r) {
    zv[r] = *(const float4*)&zr[r * 4];
    ev[r] = *(const float4*)&ek[r * 4];
  }
  #pragma unroll
  for (int r = 0; r < 4; ++r) {
    const float* zc = (const float*)&zv[r];
    const float* ec = (const float*)&ev[r];
    #pragma unroll
    for (int jj = 0; jj < 4; ++jj) {
      float zev = zc[jj];
      op[(size_t)(r * 4 + jj) * N_] = zev + (ec[jj] - zev);  // ref order
    }
  }
}

__global__ __launch_bounds__(128) void gsum_kernel(
    const float* __restrict__ ze_pm, const int* __restrict__ pos_list,
    const int* __restrict__ k_list, float* __restrict__ z_sum)
{
  const int d  = threadIdx.x;
  const int i0 = blockIdx.x * 32;
  int   kprev = -1;
  float acc = 0.f;
  #pragma unroll
  for (int ii = 0; ii < 32; ++ii) {
    int p = pos_list[i0 + ii];
    int k = k_list[i0 + ii];
    if (k != kprev) {
      if (kprev >= 0) atomicAdd(&z_sum[(size_t)kprev * D_ + d], acc);
      acc = 0.f;
      kprev = k;
    }
    acc += ze_pm[(size_t)p * D_ + d];
  }
  if (kprev >= 0) atomicAdd(&z_sum[(size_t)kprev * D_ + d], acc);
}

__global__ __launch_bounds__(256) void finalize_num_kernel(
    const float* __restrict__ ema_numer, const float* __restrict__ z_sum,
    float* __restrict__ out)
{
  const int t = blockIdx.x * 256 + threadIdx.x;
  float* out_num = out + (size_t)B_ * D_ * N_;
  out_num[t] = 0.99f * ema_numer[t] + 0.01f * z_sum[t];
}

extern "C" void kernel_launch(void* const* d_in, const int* in_sizes, int n_in,
                              void* d_out, int out_size, void* d_ws, size_t ws_size,
                              hipStream_t stream)
{
  (void)in_sizes; (void)n_in; (void)out_size; (void)ws_size;
  const float* z         = (const float*)d_in[0];
  const float* W         = (const float*)d_in[1];
  const float* emb       = (const float*)d_in[2];
  const float* ema_numer = (const float*)d_in[3];
  const float* ema_denom = (const float*)d_in[4];
  float* out = (float*)d_out;
  char*  ws  = (char*)d_ws;
  float* z_sum   = (float*)(ws + WS_ZSUM);
  int*   counts  = (int*)(ws + WS_CNT);
  int*   flagcnt = (int*)(ws + WS_FLAGC);
  int*   offsets = (int*)(ws + WS_OFF);
  float* q_sq    = (float*)(ws + WS_QSQ);
  float* q_norm  = (float*)(ws + WS_QNORM);
  int*   kstar   = (int*)(ws + WS_KSTAR);
  int*   rank    = (int*)(ws + WS_RANK);
  int*   plist   = (int*)(ws + WS_PLIST);
  int*   klist   = (int*)(ws + WS_KLIST);
  int*   flist   = (int*)(ws + WS_FLIST);
  float* Wt      = (float*)(ws + WS_WT);
  float* ze_pm   = (float*)(ws + WS_ZPM);
  float* ze_sq   = (float*)(ws + WS_ZESQ);
  float* ze_norm = (float*)(ws + WS_ZEN);
  uint4* ze2f    = (uint4*)(ws + WS_ZE2F);
  uint4* emb2f   = (uint4*)(ws + WS_EMB2F);
  float* val1    = (float*)(ws + WS_VAL1);
  int*   idx1    = (int*)(ws + WS_IDX1);
  float* val2    = (float*)(ws + WS_VAL2);
  float* out_den = out + (size_t)B_ * D_ * N_ + K_ * D_;

  // ws zeroing folded into prep_kernel (blocks 196..325)
  prep_kernel<<<326, 256, 0, stream>>>(W, emb, Wt, q_sq, q_norm, emb2f,
                                       (uint4*)ws);
  ze_kernel<<<P_ / 64, 512, 0, stream>>>(z, Wt, ze_pm, ze_sq, ze_norm, ze2f);
  mfma_argmin_kernel<<<2048, 256, 0, stream>>>(ze2f, emb2f, ze_sq, ze_norm,
                                               q_sq, q_norm, val1, idx1, val2);
  resolve_kernel<<<P_ / 256, 256, 0, stream>>>(val1, idx1, val2, kstar,
                                               rank, counts, flist, flagcnt);
  fallback_kernel<<<1024, 256, 0, stream>>>(ze_pm, emb, ze_sq, ze_norm,
                                            q_sq, q_norm, flist, flagcnt,
                                            kstar, rank, counts);
  prefix_kernel<<<1, 1024, 0, stream>>>(counts, ema_denom, offsets, out_den);
  scatter_kernel<<<P_ / 256, 256, 0, stream>>>(kstar, rank, offsets, plist, klist);
  zq_kernel<<<P_ / 64, 512, 0, stream>>>(ze_pm, emb, kstar, out);
  gsum_kernel<<<P_ / 32, 128, 0, stream>>>(ze_pm, plist, klist, z_sum);
  finalize_num_kernel<<<K_ * D_ / 256, 256, 0, stream>>>(ema_numer, z_sum, out);
}